// Round 2
// baseline (1404.423 us; speedup 1.0000x reference)
//
#include <hip/hip_runtime.h>
#include <hip/hip_bf16.h>

// RNN_80848464380442: B=64, S=2048, V=50257, E=128, H=256, C=2   (all f32, x int32)
// Stage 1: xw[b*S+t][j] = bU[j] + sum_e emb[x[b,t]][e] * W[e][j]   (emb row 0 == 0)
// Stage 2: per-batch-row sequential scan h = tanh(xw_t + h @ U), 64 independent blocks
// Stage 3: logits = h @ V + bV (fused into scan epilogue)
// Outputs concat: logits [64,2] then h [64,256], f32.

#define HB 256
#define EB 128
#define SB 2048
#define BB 64
#define TPB 16   // tokens per embed block

typedef unsigned short u16;

__device__ __forceinline__ u16 f2bf(float f) {
    union { float f; unsigned u; } x; x.f = f;
    unsigned r = x.u + 0x7fffu + ((x.u >> 16) & 1u);   // RNE
    return (u16)(r >> 16);
}
__device__ __forceinline__ float bf2f(u16 v) {
    union { unsigned u; float f; } x; x.u = ((unsigned)v) << 16; return x.f;
}

template <typename XT> __device__ __forceinline__ void st_x(XT* p, long i, float v);
template <> __device__ __forceinline__ void st_x<float>(float* p, long i, float v) { p[i] = v; }
template <> __device__ __forceinline__ void st_x<u16>(u16* p, long i, float v) { p[i] = f2bf(v); }
template <typename XT> __device__ __forceinline__ float ld_x(const XT* p, long i);
template <> __device__ __forceinline__ float ld_x<float>(const float* p, long i) { return p[i]; }
template <> __device__ __forceinline__ float ld_x<u16>(const u16* p, long i) { return bf2f(p[i]); }

// ---------------- Stage 1: embed + project (16 tokens per 256-thread block) --------
template <typename XT>
__global__ __launch_bounds__(256) void embed_proj(
    const int* __restrict__ x, const float* __restrict__ emb,
    const float* __restrict__ W, const float* __restrict__ bU,
    XT* __restrict__ xw)
{
    __shared__ __align__(16) float el[TPB][EB];   // 8 KB
    __shared__ int toks[TPB];

    const int tid = threadIdx.x;
    const long base = (long)blockIdx.x * TPB;

    if (tid < TPB) toks[tid] = x[base + tid];
    __syncthreads();

    #pragma unroll
    for (int r = 0; r < TPB * EB / 256; ++r) {
        int i = tid + r * 256;
        int row = i >> 7, e = i & (EB - 1);
        int u = toks[row];
        el[row][e] = (u == 0) ? 0.f : emb[(size_t)u * EB + e];   // padding_idx=0
    }
    __syncthreads();

    const int j = tid;
    const float bu = bU[j];
    float acc[TPB];
    #pragma unroll
    for (int t = 0; t < TPB; ++t) acc[t] = bu;

    for (int e0 = 0; e0 < EB; e0 += 4) {
        float w0 = W[(e0 + 0) * HB + j];
        float w1 = W[(e0 + 1) * HB + j];
        float w2 = W[(e0 + 2) * HB + j];
        float w3 = W[(e0 + 3) * HB + j];
        #pragma unroll
        for (int t = 0; t < TPB; ++t) {
            float4 ev = *(const float4*)&el[t][e0];   // broadcast, conflict-free
            acc[t] = fmaf(ev.x, w0, acc[t]);
            acc[t] = fmaf(ev.y, w1, acc[t]);
            acc[t] = fmaf(ev.z, w2, acc[t]);
            acc[t] = fmaf(ev.w, w3, acc[t]);
        }
    }
    #pragma unroll
    for (int t = 0; t < TPB; ++t)
        st_x<XT>(xw, (base + t) * HB + j, acc[t]);
}

// ---------------- Stage 2+3: sequential scan, one block per batch row --------------
// 1024 threads = 8 k-chunks (kk) x 128 j-pairs (jp). Thread holds U[kk*32..+32)[2jp,2jp+1]
// in 64 f32 registers. Per step: partial matvec -> LDS reduce -> tanh -> h update.
template <typename XT>
__global__ __launch_bounds__(1024) void rnn_scan(
    const XT* __restrict__ xw, const float* __restrict__ U,
    const float* __restrict__ V, const float* __restrict__ bV,
    float* __restrict__ out)
{
    __shared__ __align__(16) float hl[HB];     // h vector
    __shared__ float red[8][HB + 2];           // partial sums, padded rows

    const int tid = threadIdx.x;
    const int b = blockIdx.x;
    const int kk = tid >> 7;       // 0..7   (wave-uniform)
    const int jp = tid & 127;      // 0..127
    const int j0 = jp * 2;

    // U chunk into registers: u0/u1[c] = U[kk*32+c][2jp] / [2jp+1]
    float u0[32], u1[32];
    {
        const float2* U2 = (const float2*)U;   // row = 128 float2
        #pragma unroll
        for (int c = 0; c < 32; ++c) {
            float2 v = U2[(kk * 32 + c) * 128 + jp];
            u0[c] = v.x; u1[c] = v.y;
        }
    }

    const XT* xwb = xw + (long)b * SB * HB;
    if (tid < HB) hl[tid] = 0.f;
    float xcur = 0.f;
    if (tid < HB) xcur = ld_x<XT>(xwb, tid);   // t = 0
    __syncthreads();

    float th = 0.f;
    for (int t = 0; t < SB; ++t) {
        // prefetch next step's xw under the FMA phase
        float xnext = 0.f;
        if (tid < HB && t + 1 < SB) xnext = ld_x<XT>(xwb, (long)(t + 1) * HB + tid);

        // phase A: partial matvec (all 1024 threads, 64 FMAs each; h reads broadcast)
        float p0 = 0.f, p1 = 0.f;
        const float4* h4 = (const float4*)hl;
        #pragma unroll
        for (int c = 0; c < 8; ++c) {
            float4 hv = h4[kk * 8 + c];
            p0 = fmaf(hv.x, u0[c * 4 + 0], p0); p1 = fmaf(hv.x, u1[c * 4 + 0], p1);
            p0 = fmaf(hv.y, u0[c * 4 + 1], p0); p1 = fmaf(hv.y, u1[c * 4 + 1], p1);
            p0 = fmaf(hv.z, u0[c * 4 + 2], p0); p1 = fmaf(hv.z, u1[c * 4 + 2], p1);
            p0 = fmaf(hv.w, u0[c * 4 + 3], p0); p1 = fmaf(hv.w, u1[c * 4 + 3], p1);
        }
        red[kk][j0] = p0; red[kk][j0 + 1] = p1;
        __syncthreads();

        // phase B: reduce 8 partials, add xw, tanh, update h (first 4 waves)
        if (tid < HB) {
            float s = 0.f;
            #pragma unroll
            for (int c = 0; c < 8; ++c) s += red[c][tid];
            float z = s + xcur;
            float e = __expf(-2.f * fabsf(z));
            float a = 1.f - 2.f * e / (1.f + e);   // tanh(|z|)
            th = copysignf(a, z);
            hl[tid] = th;
        }
        xcur = xnext;
        __syncthreads();
    }

    // epilogue: h (f32) and logits
    if (tid < HB) out[BB * 2 + b * HB + tid] = th;
    if (tid < 64) {
        float s0 = 0.f, s1 = 0.f;
        const float2* V2 = (const float2*)V;    // V[j][0..1]
        #pragma unroll
        for (int r = 0; r < 4; ++r) {
            int jj = tid + r * 64;
            float hh = hl[jj];
            float2 v = V2[jj];
            s0 = fmaf(hh, v.x, s0);
            s1 = fmaf(hh, v.y, s1);
        }
        #pragma unroll
        for (int o = 32; o > 0; o >>= 1) {
            s0 += __shfl_down(s0, o);
            s1 += __shfl_down(s1, o);
        }
        if (tid == 0) {
            out[b * 2 + 0] = s0 + bV[0];
            out[b * 2 + 1] = s1 + bV[1];
        }
    }
}

extern "C" void kernel_launch(void* const* d_in, const int* in_sizes, int n_in,
                              void* d_out, int out_size, void* d_ws, size_t ws_size,
                              hipStream_t stream) {
    const int*   x   = (const int*)d_in[0];
    const float* emb = (const float*)d_in[1];
    const float* W   = (const float*)d_in[2];
    const float* U   = (const float*)d_in[3];
    const float* bU  = (const float*)d_in[4];
    const float* V   = (const float*)d_in[5];
    const float* bV  = (const float*)d_in[6];
    float* out = (float*)d_out;

    const size_t need_f32 = (size_t)BB * SB * HB * sizeof(float);   // 128 MiB
    const int nblk = BB * SB / TPB;

    if (ws_size >= need_f32) {
        float* xw = (float*)d_ws;
        embed_proj<float><<<nblk, 256, 0, stream>>>(x, emb, W, bU, xw);
        rnn_scan<float><<<BB, 1024, 0, stream>>>(xw, U, V, bV, out);
    } else {
        u16* xw = (u16*)d_ws;                                        // 64 MiB fallback
        embed_proj<u16><<<nblk, 256, 0, stream>>>(x, emb, W, bU, xw);
        rnn_scan<u16><<<BB, 1024, 0, stream>>>(xw, U, V, bV, out);
    }
}